// Round 18
// baseline (194.094 us; speedup 1.0000x reference)
//
#include <hip/hip_runtime.h>
#include <hip/hip_bf16.h>

typedef short bf16x8 __attribute__((ext_vector_type(8)));
typedef float f32x4 __attribute__((ext_vector_type(4)));
using bf16 = __hip_bfloat16;

#define Bb 8
#define Kk 2048
#define Dd 512
#define Ee 1024
#define Ss 128
#define Mrows (Bb*Kk)
#define Ff (2*Ee+Ss)

#define BM 256   // GEMM row-tile (was 128): 8 waves, half the barriers per FLOP
#define BN 128
#define BK 64

#define KVB 64   // kv step in fused attention

static __device__ __forceinline__ float bf2f(bf16 v){ return __bfloat162float(v); }
static __device__ __forceinline__ bf16 f2bf(float v){ return __float2bfloat16(v); }
static __device__ __forceinline__ unsigned int bfbits(float v){ bf16 b = __float2bfloat16(v); return (unsigned int)*(unsigned short*)&b; }

static __device__ __forceinline__ void gload16(const bf16* g, bf16* l) {
    __builtin_amdgcn_global_load_lds((const __attribute__((address_space(1))) void*)g,
                                     (__attribute__((address_space(3))) void*)l, 16, 0, 0);
}

union BV { int4 v; bf16 h[8]; };

// ---------------- fused pre-pass: rmsnorm (2 rows/block, float4) + weight casts ----------------
__global__ __launch_bounds__(256) void pre_k(const float* __restrict__ x,
                                             const float* __restrict__ g,
                                             bf16* __restrict__ xn,
                                             const float* __restrict__ w1, bf16* __restrict__ o1, int n1,
                                             const float* __restrict__ w2, bf16* __restrict__ o2, int n2) {
    int blk = blockIdx.x;
    int t = threadIdx.x;
    const int RB = Mrows / 2;
    if (blk < RB) {
        int half = t >> 7;
        int lt = t & 127;
        int row = blk * 2 + half;
        const float4* xr = (const float4*)(x + (size_t)row * Dd);
        float4 v = xr[lt];
        float ss = v.x * v.x + v.y * v.y + v.z * v.z + v.w * v.w;
        #pragma unroll
        for (int off = 32; off; off >>= 1) ss += __shfl_down(ss, off);
        __shared__ float red[4];
        if ((t & 63) == 0) red[t >> 6] = ss;
        __syncthreads();
        float tot = red[2 * half] + red[2 * half + 1];
        float norm = sqrtf(tot * (1.0f / Dd));
        float scale = g[0] / fmaxf(norm, 1e-5f);
        ushort4 w;
        w.x = (unsigned short)bfbits(v.x * scale);
        w.y = (unsigned short)bfbits(v.y * scale);
        w.z = (unsigned short)bfbits(v.z * scale);
        w.w = (unsigned short)bfbits(v.w * scale);
        *(ushort4*)&xn[(size_t)row * Dd + lt * 4] = w;
    } else {
        int i = (blk - RB) * 256 + t;
        if (i < n1) o1[i] = f2bf(w1[i]);
        else if (i < n1 + n2) o2[i - n1] = f2bf(w2[i - n1]);
    }
}

// ---------------- GEMM 256x128 tile, 512 threads = 8 waves (4 row x 2 col of 64x64) ----------------
// Staging: A 32K + B 16K per buf, double-buffered = 96 KB -> 1 block/CU (8 waves,
// same occupancy as the old 2x4-wave config) with HALF the barrier crossings per FLOP.
// Same XOR chunk swizzle (row&7 == fr&7 preserved).
template<int EPI>
__global__ __launch_bounds__(512, 2)
void gemm_nt(const bf16* __restrict__ A, int lda,
             const bf16* __restrict__ B, int ldb, int nk, int nTN,
             bf16* __restrict__ u, bf16* __restrict__ vT,
             bf16* __restrict__ qb, bf16* __restrict__ kb,
             const float* __restrict__ gamma, const float* __restrict__ beta,
             const float* __restrict__ x, const float* __restrict__ rsc,
             float* __restrict__ out) {
    __shared__ char smem[98304];   // 2 x (A 32768 + B 16384)

    const int t = threadIdx.x;
    const int bid = blockIdx.x;
    const int xcd = bid & 7;
    const int ii  = bid >> 3;
    const int tM = xcd * 8 + ii / nTN;   // 64 row-tiles, 8 per XCD
    const int tN = ii % nTN;
    const int rowM = tM * BM;

    const bf16* Ab = A + (size_t)rowM * lda;
    const bf16* Bp = B + (size_t)tN * BN * ldb;

    const int lane = t & 63;
    const int wave = t >> 6;              // 0..7
    const int wr = (wave >> 1) * 64;      // 0,64,128,192
    const int wc = (wave & 1) * 64;       // 0,64
    const int fr = lane & 15;
    const int h  = lane >> 4;
    const int q4 = h * 4;

    auto stage = [&](int buf, int k0) {
        bf16* Al = (bf16*)(smem + buf * 49152);
        bf16* Bl = Al + 16384;
        #pragma unroll
        for (int it = 0; it < 4; ++it) {       // A: 256 r x 8 chunks = 2048 slots
            int idx = t + it * 512;
            int r = idx >> 3, cp = idx & 7;
            int cg = (cp ^ r) & 7;
            gload16(Ab + (size_t)r * lda + k0 + cg * 8, Al + idx * 8);
        }
        #pragma unroll
        for (int it = 0; it < 2; ++it) {       // B: 128 r x 8 chunks = 1024 slots
            int idx = t + it * 512;
            int r = idx >> 3, cp = idx & 7;
            int cg = (cp ^ r) & 7;
            gload16(Bp + (size_t)r * ldb + k0 + cg * 8, Bl + idx * 8);
        }
    };

    f32x4 acc[4][4] = {};
    int cur = 0;
    stage(0, 0);
    for (int kt = 0; kt < nk; ++kt) {
        __syncthreads();
        if (kt + 1 < nk) stage(cur ^ 1, (kt + 1) * BK);
        const bf16* Asl = (const bf16*)(smem + cur * 49152);
        const bf16* Bsl = Asl + 16384;
        #pragma unroll
        for (int kk = 0; kk < 2; ++kk) {
            const int cs = ((4 * kk + h) ^ (fr & 7)) * 8;
            bf16x8 af[4], bv[4];
            #pragma unroll
            for (int m = 0; m < 4; ++m) af[m] = *(const bf16x8*)&Asl[(wr + m * 16 + fr) * BK + cs];
            #pragma unroll
            for (int n = 0; n < 4; ++n) bv[n] = *(const bf16x8*)&Bsl[(wc + n * 16 + fr) * BK + cs];
            #pragma unroll
            for (int m = 0; m < 4; ++m)
                #pragma unroll
                for (int n = 0; n < 4; ++n)
                    acc[m][n] = __builtin_amdgcn_mfma_f32_16x16x32_bf16(af[m], bv[n], acc[m][n], 0, 0, 0);
        }
        cur ^= 1;
    }
    __syncthreads();

    if (EPI == 0) {
        const bool isV = (tN >= 8 && tN < 16);
        bf16 (*Ot)[136]  = (bf16(*)[136])smem;    // normal: 256x136x2 = 69632 <= 98304
        bf16 (*Ot2)[264] = (bf16(*)[264])smem;    // transposed view: 128x264x2 = 67584
        #pragma unroll
        for (int m = 0; m < 4; ++m)
            #pragma unroll
            for (int n = 0; n < 4; ++n)
                #pragma unroll
                for (int j = 0; j < 4; ++j) {
                    float val = acc[m][n][j];
                    float s = val / (1.0f + __expf(-val));
                    int rr = wr + m * 16 + q4 + j;      // 0..255
                    int cc = wc + n * 16 + fr;          // 0..127
                    if (isV) Ot2[cc][rr] = f2bf(s);
                    else     Ot[rr][cc]  = f2bf(s);
                }
        __syncthreads();
        if (tN < 8) {                                   // ---- u region
            bf16* dst = u + (size_t)rowM * Ee + tN * 128;
            #pragma unroll
            for (int i = 0; i < 8; ++i) {
                int idx = t + i * 512;
                int r = idx >> 4, c = (idx & 15) * 8;   // 256 r x 16 chunks
                *(int4*)&dst[(size_t)r * Ee + c] = *(const int4*)&Ot[r][c];
            }
        } else if (tN < 16) {                           // ---- v region -> vT directly
            int b  = rowM >> 11;
            int j0 = rowM & 2047;                       // rowM mult of 256, batch 2048 divisible
            bf16* dst = vT + (size_t)b * Ee * Kk + (size_t)(tN - 8) * 128 * Kk + j0;
            #pragma unroll
            for (int i = 0; i < 8; ++i) {
                int idx = t + i * 512;
                int e = idx >> 5, c = (idx & 31) * 8;   // 128 e x 32 chunks (256 j)
                *(int4*)&dst[(size_t)e * Kk + c] = *(const int4*)&Ot2[e][c];
            }
        } else {                                        // ---- q/k region
            #pragma unroll
            for (int i = 0; i < 8; ++i) {
                int idx = t + i * 512;
                int r = idx >> 4, c = (idx & 15) * 8;
                BV sv; sv.v = *(const int4*)&Ot[r][c];
                BV qv, kv;
                #pragma unroll
                for (int e2 = 0; e2 < 8; ++e2) {
                    float s = bf2f(sv.h[e2]);
                    qv.h[e2] = f2bf(s * gamma[c + e2]       + beta[c + e2]);
                    kv.h[e2] = f2bf(s * gamma[128 + c + e2] + beta[128 + c + e2]);
                }
                *(int4*)&qb[(size_t)(rowM + r) * Ss + c] = qv.v;
                *(int4*)&kb[(size_t)(rowM + r) * Ss + c] = kv.v;
            }
        }
    } else {
        float (*Of)[132] = (float(*)[132])smem;   // 128x132x4 = 67584 <= 98304
        const int col0 = tN * 128;
        #pragma unroll
        for (int hh = 0; hh < 2; ++hh) {          // two 128-row passes
            if (hh) __syncthreads();
            if ((wave >> 2) == hh) {
                int lwr = wr & 127;
                #pragma unroll
                for (int m = 0; m < 4; ++m)
                    #pragma unroll
                    for (int n = 0; n < 4; ++n)
                        #pragma unroll
                        for (int j = 0; j < 4; ++j)
                            Of[lwr + m * 16 + q4 + j][wc + n * 16 + fr] = acc[m][n][j];
            }
            __syncthreads();
            #pragma unroll
            for (int i = 0; i < 8; ++i) {
                int idx = t + i * 512;
                int r = idx >> 5, c4 = (idx & 31) * 4;   // 128 r x 32 float4
                size_t row = (size_t)(rowM + hh * 128 + r);
                float4 v  = *(const float4*)&Of[r][c4];
                float4 xv = *(const float4*)&x[row * Dd + col0 + c4];
                float4 rv = *(const float4*)&rsc[col0 + c4];
                float4 o;
                o.x = xv.x * rv.x + v.x;  o.y = xv.y * rv.y + v.y;
                o.z = xv.z * rv.z + v.z;  o.w = xv.w * rv.w + v.w;
                *(float4*)&out[row * Dd + col0 + c4] = o;
            }
        }
    }
}

// ---------------- fused attention: agg = u * (relu(QK^T/sqrt(S))^2 @ V) ----------------
// r14/r17 kernel VERBATIM (best measured attn ~102.5 us; structural floor:
// 64 VGPR + 64 AGPR = 128 regs/thread -> 16 waves/CU cap).
__global__ __launch_bounds__(1024, 4)
void attn_fused(const bf16* __restrict__ qg, const bf16* __restrict__ kg,
                const bf16* __restrict__ vTg, const bf16* __restrict__ ug,
                bf16* __restrict__ aggg) {
    __shared__ char smem[163840];
    bf16* Kbuf = (bf16*)smem;
    bf16* Vbuf = (bf16*)(smem + 16384);
    bf16* Pbuf = (bf16*)(smem + 147456);

    const int blk = blockIdx.x;
    const int b  = blk & 7;
    const int t2 = blk >> 3;
    const int tE = t2 & 1;
    const int tQ = t2 >> 1;

    const bf16* Qp = qg  + ((size_t)b * Kk + (size_t)tQ * 128) * Ss;
    const bf16* Kg = kg  + (size_t)b * Kk * Ss;
    const bf16* Vg = vTg + (size_t)b * Ee * Kk + (size_t)(tE * 512) * Kk;

    const int t = threadIdx.x;
    const int lane = t & 63, wave = t >> 6;
    const int fr = lane & 15;
    const int h  = lane >> 4;
    const int q4 = h * 4;
    const int f3 = fr & 7;

    const int qgp = wave & 7, kvh = wave >> 3;
    const int wm = wave >> 3, wn = wave & 7;

    bf16x8 qf[4];
    #pragma unroll
    for (int ks = 0; ks < 4; ++ks)
        qf[ks] = *(const bf16x8*)(Qp + (size_t)(16 * qgp + fr) * Ss + 32 * ks + h * 8);

    auto stage = [&](int vbuf, int kvt) {
        const bf16* Kgt = Kg + (size_t)kvt * KVB * Ss;
        const bf16* Vgt = Vg + (size_t)kvt * KVB;
        bf16* Vl = Vbuf + vbuf * 32768;
        {
            int r = t >> 4, cp = t & 15;
            int cg = (cp & 8) | ((cp ^ (r & 7)) & 7);
            gload16(Kgt + (size_t)r * Ss + cg * 8, Kbuf + t * 8);
        }
        #pragma unroll
        for (int it = 0; it < 4; ++it) {
            int idx = t + it * 1024;
            int r = idx >> 3, cp = idx & 7;
            int cg = cp ^ (r & 7);
            gload16(Vgt + (size_t)r * Kk + cg * 8, Vl + idx * 8);
        }
    };

    f32x4 acc[4][4] = {};
    const int NT = Kk / KVB;
    stage(0, 0);

    for (int kv = 0; kv < NT; ++kv) {
        const int cur = kv & 1;
        __syncthreads();

        f32x4 accS[2] = {};
        __builtin_amdgcn_s_setprio(1);
        #pragma unroll
        for (int ks = 0; ks < 4; ++ks) {
            #pragma unroll
            for (int c = 0; c < 2; ++c) {
                int cgk = 4 * ks + h;
                int cs = (cgk & 8) | ((cgk ^ f3) & 7);
                bf16x8 af = *(const bf16x8*)&Kbuf[(32 * kvh + 16 * c + fr) * 128 + cs * 8];
                accS[c] = __builtin_amdgcn_mfma_f32_16x16x32_bf16(af, qf[ks], accS[c], 0, 0, 0);
            }
        }
        __builtin_amdgcn_s_setprio(0);
        #pragma unroll
        for (int c = 0; c < 2; ++c) {
            int rowP = 16 * qgp + fr;
            float sv[4];
            #pragma unroll
            for (int j = 0; j < 4; ++j) {
                float s = accS[c][j] * 0.08838834764831845f;
                s = fmaxf(s, 0.0f);
                sv[j] = s * s;
            }
            uint2 w;
            w.x = bfbits(sv[0]) | (bfbits(sv[1]) << 16);
            w.y = bfbits(sv[2]) | (bfbits(sv[3]) << 16);
            int sc = (4 * kvh + 2 * c + (h >> 1)) ^ f3;
            *(uint2*)&Pbuf[rowP * 64 + sc * 8 + 4 * (h & 1)] = w;
        }
        __syncthreads();

        if (kv + 1 < NT) stage(cur ^ 1, kv + 1);

        const bf16* Vl = Vbuf + cur * 32768;
        __builtin_amdgcn_s_setprio(1);
        #pragma unroll
        for (int kk = 0; kk < 2; ++kk) {
            const int cs = ((4 * kk + h) ^ f3) * 8;
            bf16x8 af[4], bv[4];
            #pragma unroll
            for (int m = 0; m < 4; ++m) {
                int row = wm * 64 + m * 16 + fr;
                af[m] = *(const bf16x8*)&Pbuf[row * 64 + cs];
            }
            #pragma unroll
            for (int n = 0; n < 4; ++n) {
                int row = wn * 64 + n * 16 + fr;
                bv[n] = *(const bf16x8*)&Vl[row * 64 + cs];
            }
            #pragma unroll
            for (int m = 0; m < 4; ++m)
                #pragma unroll
                for (int n = 0; n < 4; ++n)
                    acc[m][n] = __builtin_amdgcn_mfma_f32_16x16x32_bf16(af[m], bv[n], acc[m][n], 0, 0, 0);
        }
        __builtin_amdgcn_s_setprio(0);
    }

    bf16 (*Ot)[136] = (bf16(*)[136])smem;
    const size_t rowbase = (size_t)b * Kk + (size_t)tQ * 128;
    #pragma unroll
    for (int s = 0; s < 4; ++s) {
        __syncthreads();
        if ((wn >> 1) == s) {
            #pragma unroll
            for (int m = 0; m < 4; ++m)
                #pragma unroll
                for (int n = 0; n < 4; ++n)
                    #pragma unroll
                    for (int j = 0; j < 4; ++j)
                        Ot[wm * 64 + m * 16 + q4 + j][(wn & 1) * 64 + n * 16 + fr] = f2bf(acc[m][n][j]);
        }
        __syncthreads();
        const bf16* usrc = ug   + rowbase * Ee + tE * 512 + s * 128;
        bf16*       adst = aggg + rowbase * Ee + tE * 512 + s * 128;
        #pragma unroll
        for (int i = 0; i < 2; ++i) {
            int idx = t + i * 1024;
            int r = idx >> 4, c = (idx & 15) * 8;
            BV ov, uv2, rv;
            ov.v  = *(const int4*)&Ot[r][c];
            uv2.v = *(const int4*)&usrc[(size_t)r * Ee + c];
            #pragma unroll
            for (int e2 = 0; e2 < 8; ++e2) rv.h[e2] = f2bf(bf2f(ov.h[e2]) * bf2f(uv2.h[e2]));
            *(int4*)&adst[(size_t)r * Ee + c] = rv.v;
        }
    }
}

extern "C" void kernel_launch(void* const* d_in, const int* in_sizes, int n_in,
                              void* d_out, int out_size, void* d_ws, size_t ws_size,
                              hipStream_t stream) {
    const float* x         = (const float*)d_in[0];
    const float* uv_w      = (const float*)d_in[1];
    const float* o_w       = (const float*)d_in[2];
    const float* gamma     = (const float*)d_in[3];
    const float* beta      = (const float*)d_in[4];
    const float* g         = (const float*)d_in[5];
    const float* res_scale = (const float*)d_in[6];
    float* out = (float*)d_out;

    char* ws = (char*)d_ws;
    size_t off = 0;
    auto alloc = [&](size_t bytes) { void* p = ws + off; off += (bytes + 255) & ~(size_t)255; return p; };

    bf16* xn   = (bf16*)alloc((size_t)Mrows * Dd * 2);
    bf16* uvwb = (bf16*)alloc((size_t)Ff * Dd * 2);
    bf16* owb  = (bf16*)alloc((size_t)Dd * Ee * 2);
    bf16* u    = (bf16*)alloc((size_t)Mrows * Ee * 2);
    bf16* qb   = (bf16*)alloc((size_t)Mrows * Ss * 2);
    bf16* kb   = (bf16*)alloc((size_t)Mrows * Ss * 2);
    bf16* agg  = (bf16*)alloc((size_t)Mrows * Ee * 2);
    bf16* vT   = (bf16*)alloc((size_t)Bb * Ee * Kk * 2);

    int n1 = Ff * Dd;
    int n2 = Dd * Ee;
    int castBlocks = (n1 + n2 + 255) / 256;

    // fused rmsnorm (2 rows/block, float4) + weight casts
    pre_k<<<Mrows / 2 + castBlocks, 256, 0, stream>>>(x, g, xn, uv_w, uvwb, n1, o_w, owb, n2);

    // GEMM1: silu(xn @ uv_w^T) -> u, vT (transposed), q, k.  grid 64 tM x 17 tN = 1088
    gemm_nt<0><<<1088, 512, 0, stream>>>(
        xn, Dd, uvwb, Dd, Dd / BK, 17,
        u, vT, qb, kb, gamma, beta, nullptr, nullptr, nullptr);

    // fused attention: 256 blocks x 1024 threads
    attn_fused<<<256, 1024, 0, stream>>>(qb, kb, vT, u, agg);

    // GEMM4: out = x*res_scale + agg @ o_w^T.  grid 64 tM x 4 tN = 256
    gemm_nt<3><<<256, 512, 0, stream>>>(
        agg, Ee, owb, Ee, Ee / BK, 4,
        nullptr, nullptr, nullptr, nullptr, nullptr, nullptr,
        x, res_scale, out);
}

// Round 19
// 183.661 us; speedup vs baseline: 1.0568x; 1.0568x over previous
//
#include <hip/hip_runtime.h>
#include <hip/hip_bf16.h>

typedef short bf16x8 __attribute__((ext_vector_type(8)));
typedef float f32x4 __attribute__((ext_vector_type(4)));
using bf16 = __hip_bfloat16;

#define Bb 8
#define Kk 2048
#define Dd 512
#define Ee 1024
#define Ss 128
#define Mrows (Bb*Kk)
#define Ff (2*Ee+Ss)

#define BM 128
#define BN 128
#define BK 64

#define KVB 64   // kv step in fused attention

static __device__ __forceinline__ float bf2f(bf16 v){ return __bfloat162float(v); }
static __device__ __forceinline__ bf16 f2bf(float v){ return __float2bfloat16(v); }
static __device__ __forceinline__ unsigned int bfbits(float v){ bf16 b = __float2bfloat16(v); return (unsigned int)*(unsigned short*)&b; }

static __device__ __forceinline__ void gload16(const bf16* g, bf16* l) {
    __builtin_amdgcn_global_load_lds((const __attribute__((address_space(1))) void*)g,
                                     (__attribute__((address_space(3))) void*)l, 16, 0, 0);
}

union BV { int4 v; bf16 h[8]; };

// ---------------- fused pre-pass: rmsnorm (2 rows/block, float4) + weight casts ----------------
__global__ __launch_bounds__(256) void pre_k(const float* __restrict__ x,
                                             const float* __restrict__ g,
                                             bf16* __restrict__ xn,
                                             const float* __restrict__ w1, bf16* __restrict__ o1, int n1,
                                             const float* __restrict__ w2, bf16* __restrict__ o2, int n2) {
    int blk = blockIdx.x;
    int t = threadIdx.x;
    const int RB = Mrows / 2;                 // rmsnorm blocks: 2 rows each
    if (blk < RB) {
        int half = t >> 7;                    // 0..1 -> row within pair
        int lt = t & 127;                     // 128 lanes x float4 = 512 f32 = one row
        int row = blk * 2 + half;
        const float4* xr = (const float4*)(x + (size_t)row * Dd);
        float4 v = xr[lt];
        float ss = v.x * v.x + v.y * v.y + v.z * v.z + v.w * v.w;
        #pragma unroll
        for (int off = 32; off; off >>= 1) ss += __shfl_down(ss, off);
        __shared__ float red[4];
        if ((t & 63) == 0) red[t >> 6] = ss;
        __syncthreads();
        float tot = red[2 * half] + red[2 * half + 1];
        float norm = sqrtf(tot * (1.0f / Dd));
        float scale = g[0] / fmaxf(norm, 1e-5f);
        ushort4 w;
        w.x = (unsigned short)bfbits(v.x * scale);
        w.y = (unsigned short)bfbits(v.y * scale);
        w.z = (unsigned short)bfbits(v.z * scale);
        w.w = (unsigned short)bfbits(v.w * scale);
        *(ushort4*)&xn[(size_t)row * Dd + lt * 4] = w;
    } else {
        int i = (blk - RB) * 256 + t;
        if (i < n1) o1[i] = f2bf(w1[i]);
        else if (i < n1 + n2) o2[i - n1] = f2bf(w2[i - n1]);
    }
}

// ---------------- GEMM (global_load_lds, linear LDS + XOR swizzle, dbuf, BK=64) ----------------
template<int EPI>
__global__ __launch_bounds__(256, 2)
void gemm_nt(const bf16* __restrict__ A, int lda,
             const bf16* __restrict__ B, int ldb, int nk, int nTN,
             bf16* __restrict__ u, bf16* __restrict__ vT,
             bf16* __restrict__ qb, bf16* __restrict__ kb,
             const float* __restrict__ gamma, const float* __restrict__ beta,
             const float* __restrict__ x, const float* __restrict__ rsc,
             float* __restrict__ out) {
    __shared__ char smem[65536];

    const int t = threadIdx.x;
    const int bid = blockIdx.x;
    const int xcd = bid & 7;
    const int ii  = bid >> 3;
    const int tM = xcd * 16 + ii / nTN;
    const int tN = ii % nTN;
    const int rowM = tM * BM;

    const bf16* Ab = A + (size_t)rowM * lda;
    const bf16* Bp = B + (size_t)tN * BN * ldb;

    const int lane = t & 63;
    const int wave = t >> 6;
    const int wr = (wave >> 1) * 64, wc = (wave & 1) * 64;
    const int fr = lane & 15;
    const int h  = lane >> 4;
    const int q4 = h * 4;

    auto stage = [&](int buf, int k0) {
        bf16* Al = (bf16*)(smem + buf * 32768);
        bf16* Bl = Al + 8192;
        #pragma unroll
        for (int it = 0; it < 4; ++it) {
            int idx = t + it * 256;
            int r = idx >> 3, cp = idx & 7;
            int cg = (cp ^ r) & 7;
            gload16(Ab + (size_t)r * lda + k0 + cg * 8, Al + idx * 8);
            gload16(Bp + (size_t)r * ldb + k0 + cg * 8, Bl + idx * 8);
        }
    };

    f32x4 acc[4][4] = {};
    int cur = 0;
    stage(0, 0);
    for (int kt = 0; kt < nk; ++kt) {
        __syncthreads();
        if (kt + 1 < nk) stage(cur ^ 1, (kt + 1) * BK);
        const bf16* Asl = (const bf16*)(smem + cur * 32768);
        const bf16* Bsl = Asl + 8192;
        #pragma unroll
        for (int kk = 0; kk < 2; ++kk) {
            const int cs = ((4 * kk + h) ^ (fr & 7)) * 8;
            bf16x8 af[4], bv[4];
            #pragma unroll
            for (int m = 0; m < 4; ++m) af[m] = *(const bf16x8*)&Asl[(wr + m * 16 + fr) * BK + cs];
            #pragma unroll
            for (int n = 0; n < 4; ++n) bv[n] = *(const bf16x8*)&Bsl[(wc + n * 16 + fr) * BK + cs];
            #pragma unroll
            for (int m = 0; m < 4; ++m)
                #pragma unroll
                for (int n = 0; n < 4; ++n)
                    acc[m][n] = __builtin_amdgcn_mfma_f32_16x16x32_bf16(af[m], bv[n], acc[m][n], 0, 0, 0);
        }
        cur ^= 1;
    }
    __syncthreads();

    if (EPI == 0) {
        bf16 (*Ot)[140] = (bf16(*)[140])smem;
        const bool isV = (tN >= 8 && tN < 16);
        #pragma unroll
        for (int m = 0; m < 4; ++m)
            #pragma unroll
            for (int n = 0; n < 4; ++n)
                #pragma unroll
                for (int j = 0; j < 4; ++j) {
                    float val = acc[m][n][j];
                    float s = val / (1.0f + __expf(-val));
                    int rr = wr + m * 16 + q4 + j;
                    int cc = wc + n * 16 + fr;
                    if (isV) Ot[cc][rr] = f2bf(s);
                    else     Ot[rr][cc] = f2bf(s);
                }
        __syncthreads();
        if (tN < 8) {
            bf16* dst = u + (size_t)rowM * Ee + tN * 128;
            #pragma unroll
            for (int i = 0; i < 8; ++i) {
                int r = wave * 32 + (lane >> 4) + i * 4;
                int c = (lane & 15) * 8;
                *(int4*)&dst[(size_t)r * Ee + c] = *(const int4*)&Ot[r][c];
            }
        } else if (tN < 16) {
            int b  = rowM >> 11;
            int j0 = rowM & 2047;
            bf16* dst = vT + (size_t)b * Ee * Kk + (size_t)(tN - 8) * 128 * Kk + j0;
            #pragma unroll
            for (int i = 0; i < 8; ++i) {
                int e = wave * 32 + (lane >> 4) + i * 4;
                int c = (lane & 15) * 8;
                *(int4*)&dst[(size_t)e * Kk + c] = *(const int4*)&Ot[e][c];
            }
        } else {
            #pragma unroll
            for (int i = 0; i < 8; ++i) {
                int r = wave * 32 + (lane >> 4) + i * 4;
                int c = (lane & 15) * 8;
                BV sv; sv.v = *(const int4*)&Ot[r][c];
                BV qv, kv;
                #pragma unroll
                for (int e2 = 0; e2 < 8; ++e2) {
                    float s = bf2f(sv.h[e2]);
                    qv.h[e2] = f2bf(s * gamma[c + e2]       + beta[c + e2]);
                    kv.h[e2] = f2bf(s * gamma[128 + c + e2] + beta[128 + c + e2]);
                }
                *(int4*)&qb[(size_t)(rowM + r) * Ss + c] = qv.v;
                *(int4*)&kb[(size_t)(rowM + r) * Ss + c] = kv.v;
            }
        }
    } else {
        float (*Of)[134] = (float(*)[134])smem;
        const int col0 = tN * 128;
        #pragma unroll
        for (int hh = 0; hh < 2; ++hh) {
            if (hh) __syncthreads();
            if ((wave >> 1) == hh) {
                #pragma unroll
                for (int m = 0; m < 4; ++m)
                    #pragma unroll
                    for (int n = 0; n < 4; ++n)
                        #pragma unroll
                        for (int j = 0; j < 4; ++j)
                            Of[m * 16 + q4 + j][wc + n * 16 + fr] = acc[m][n][j];
            }
            __syncthreads();
            #pragma unroll
            for (int i = 0; i < 8; ++i) {
                int idx = t + i * 256;
                int r = idx >> 5, c4 = (idx & 31) * 4;
                size_t row = (size_t)(rowM + hh * 64 + r);
                float4 v  = *(const float4*)&Of[r][c4];
                float4 xv = *(const float4*)&x[row * Dd + col0 + c4];
                float4 rv = *(const float4*)&rsc[col0 + c4];
                float4 o;
                o.x = xv.x * rv.x + v.x;  o.y = xv.y * rv.y + v.y;
                o.z = xv.z * rv.z + v.z;  o.w = xv.w * rv.w + v.w;
                *(float4*)&out[row * Dd + col0 + c4] = o;
            }
        }
    }
}

// ---------------- fused attention: agg = u * (relu(QK^T/sqrt(S))^2 @ V) ----------------
// r14 kernel VERBATIM (best measured attn: ~102 us). 1024 threads = 16 waves,
// q-tile 128 x e-tile 512, KVB=64, 2 __syncthreads/iter, K single-buffered,
// V double-buffered, stage issued after the MID barrier. Register-capped at
// 16 waves/CU (64 VGPR + 64 AGPR = 128/thread = full file) -- structural floor.
__global__ __launch_bounds__(1024, 4)
void attn_fused(const bf16* __restrict__ qg, const bf16* __restrict__ kg,
                const bf16* __restrict__ vTg, const bf16* __restrict__ ug,
                bf16* __restrict__ aggg) {
    __shared__ char smem[163840];
    bf16* Kbuf = (bf16*)smem;                  // 8192 bf16: [64][128], single buffer
    bf16* Vbuf = (bf16*)(smem + 16384);        // 2 x 32768 bf16: [512][64]
    bf16* Pbuf = (bf16*)(smem + 147456);       // 8192 bf16: [128 q][64 kv], chunk-swizzled

    const int blk = blockIdx.x;                // 256 blocks
    const int b  = blk & 7;
    const int t2 = blk >> 3;                   // 0..31
    const int tE = t2 & 1;                     // e-tile 0..1 (512 cols)
    const int tQ = t2 >> 1;                    // q-tile 0..15

    const bf16* Qp = qg  + ((size_t)b * Kk + (size_t)tQ * BM) * Ss;
    const bf16* Kg = kg  + (size_t)b * Kk * Ss;
    const bf16* Vg = vTg + (size_t)b * Ee * Kk + (size_t)(tE * 512) * Kk;

    const int t = threadIdx.x;
    const int lane = t & 63, wave = t >> 6;    // wave 0..15
    const int fr = lane & 15;
    const int h  = lane >> 4;
    const int q4 = h * 4;
    const int f3 = fr & 7;                     // row-derived swizzle key

    // S roles: qgp 0..7 (16-row q-group), kvh 0..1 (32-row kv-half)
    const int qgp = wave & 7, kvh = wave >> 3;
    // PV roles: wm 0..1 (64-row q-half), wn 0..7 (64-col e-slice)
    const int wm = wave >> 3, wn = wave & 7;

    // Q fragments (iter-invariant, B-operand): q-row = 16*qgp + fr
    bf16x8 qf[4];
    #pragma unroll
    for (int ks = 0; ks < 4; ++ks)
        qf[ks] = *(const bf16x8*)(Qp + (size_t)(16 * qgp + fr) * Ss + 32 * ks + h * 8);

    auto stage = [&](int vbuf, int kvt) {
        const bf16* Kgt = Kg + (size_t)kvt * KVB * Ss;
        const bf16* Vgt = Vg + (size_t)kvt * KVB;
        bf16* Vl = Vbuf + vbuf * 32768;
        {   // K: 64 rows x 16 chunks = 1024 slots, 1/thread -> single Kbuf
            int r = t >> 4, cp = t & 15;
            int cg = (cp & 8) | ((cp ^ (r & 7)) & 7);
            gload16(Kgt + (size_t)r * Ss + cg * 8, Kbuf + t * 8);
        }
        #pragma unroll
        for (int it = 0; it < 4; ++it) {   // V: 512 rows x 8 chunks = 4096 slots
            int idx = t + it * 1024;
            int r = idx >> 3, cp = idx & 7;
            int cg = cp ^ (r & 7);
            gload16(Vgt + (size_t)r * Kk + cg * 8, Vl + idx * 8);
        }
    };

    f32x4 acc[4][4] = {};
    const int NT = Kk / KVB;   // 32
    stage(0, 0);

    for (int kv = 0; kv < NT; ++kv) {
        const int cur = kv & 1;
        __syncthreads();   // staged K + V[cur] ready (vmcnt drained); Pbuf free

        // ---- S-phase (swapped): accS[c] = K[32*kvh + 16*c + fr][:] x Q[16*qgp + fr][:]
        f32x4 accS[2] = {};
        __builtin_amdgcn_s_setprio(1);
        #pragma unroll
        for (int ks = 0; ks < 4; ++ks) {
            #pragma unroll
            for (int c = 0; c < 2; ++c) {
                int cgk = 4 * ks + h;
                int cs = (cgk & 8) | ((cgk ^ f3) & 7);
                bf16x8 af = *(const bf16x8*)&Kbuf[(32 * kvh + 16 * c + fr) * 128 + cs * 8];
                accS[c] = __builtin_amdgcn_mfma_f32_16x16x32_bf16(af, qf[ks], accS[c], 0, 0, 0);
            }
        }
        __builtin_amdgcn_s_setprio(0);
        // relu^2 -> P. lane holds S[kv=32kvh+16c+q4+j][q=16qgp+fr]
        #pragma unroll
        for (int c = 0; c < 2; ++c) {
            int rowP = 16 * qgp + fr;
            float sv[4];
            #pragma unroll
            for (int j = 0; j < 4; ++j) {
                float s = accS[c][j] * 0.08838834764831845f;
                s = fmaxf(s, 0.0f);
                sv[j] = s * s;
            }
            uint2 w;
            w.x = bfbits(sv[0]) | (bfbits(sv[1]) << 16);
            w.y = bfbits(sv[2]) | (bfbits(sv[3]) << 16);
            int sc = (4 * kvh + 2 * c + (h >> 1)) ^ f3;
            *(uint2*)&Pbuf[rowP * 64 + sc * 8 + 4 * (h & 1)] = w;
        }
        __syncthreads();   // P visible; S-phase K reads complete

        if (kv + 1 < NT) stage(cur ^ 1, kv + 1);   // K single-buf safe (reads done);
                                                   // drains at next top barrier under PV cover

        // ---- PV: acc += P[wm*64..][64] @ V[64][wn*64..]
        const bf16* Vl = Vbuf + cur * 32768;
        __builtin_amdgcn_s_setprio(1);
        #pragma unroll
        for (int kk = 0; kk < 2; ++kk) {
            const int cs = ((4 * kk + h) ^ f3) * 8;
            bf16x8 af[4], bv[4];
            #pragma unroll
            for (int m = 0; m < 4; ++m) {
                int row = wm * 64 + m * 16 + fr;
                af[m] = *(const bf16x8*)&Pbuf[row * 64 + cs];
            }
            #pragma unroll
            for (int n = 0; n < 4; ++n) {
                int row = wn * 64 + n * 16 + fr;
                bv[n] = *(const bf16x8*)&Vl[row * 64 + cs];
            }
            #pragma unroll
            for (int m = 0; m < 4; ++m)
                #pragma unroll
                for (int n = 0; n < 4; ++n)
                    acc[m][n] = __builtin_amdgcn_mfma_f32_16x16x32_bf16(af[m], bv[n], acc[m][n], 0, 0, 0);
        }
        __builtin_amdgcn_s_setprio(0);
    }

    // ---- epilogue in four 128-col passes: agg = acc * u
    bf16 (*Ot)[136] = (bf16(*)[136])smem;   // 128x136x2 = 34816 <= 163840
    const size_t rowbase = (size_t)b * Kk + (size_t)tQ * BM;
    #pragma unroll
    for (int s = 0; s < 4; ++s) {
        __syncthreads();
        if ((wn >> 1) == s) {
            #pragma unroll
            for (int m = 0; m < 4; ++m)
                #pragma unroll
                for (int n = 0; n < 4; ++n)
                    #pragma unroll
                    for (int j = 0; j < 4; ++j)
                        Ot[wm * 64 + m * 16 + q4 + j][(wn & 1) * 64 + n * 16 + fr] = f2bf(acc[m][n][j]);
        }
        __syncthreads();
        const bf16* usrc = ug   + rowbase * Ee + tE * 512 + s * 128;
        bf16*       adst = aggg + rowbase * Ee + tE * 512 + s * 128;
        #pragma unroll
        for (int i = 0; i < 2; ++i) {
            int idx = t + i * 1024;
            int r = idx >> 4, c = (idx & 15) * 8;
            BV ov, uv2, rv;
            ov.v  = *(const int4*)&Ot[r][c];
            uv2.v = *(const int4*)&usrc[(size_t)r * Ee + c];
            #pragma unroll
            for (int e2 = 0; e2 < 8; ++e2) rv.h[e2] = f2bf(bf2f(ov.h[e2]) * bf2f(uv2.h[e2]));
            *(int4*)&adst[(size_t)r * Ee + c] = rv.v;
        }
    }
}

extern "C" void kernel_launch(void* const* d_in, const int* in_sizes, int n_in,
                              void* d_out, int out_size, void* d_ws, size_t ws_size,
                              hipStream_t stream) {
    const float* x         = (const float*)d_in[0];
    const float* uv_w      = (const float*)d_in[1];
    const float* o_w       = (const float*)d_in[2];
    const float* gamma     = (const float*)d_in[3];
    const float* beta      = (const float*)d_in[4];
    const float* g         = (const float*)d_in[5];
    const float* res_scale = (const float*)d_in[6];
    float* out = (float*)d_out;

    char* ws = (char*)d_ws;
    size_t off = 0;
    auto alloc = [&](size_t bytes) { void* p = ws + off; off += (bytes + 255) & ~(size_t)255; return p; };

    bf16* xn   = (bf16*)alloc((size_t)Mrows * Dd * 2);
    bf16* uvwb = (bf16*)alloc((size_t)Ff * Dd * 2);
    bf16* owb  = (bf16*)alloc((size_t)Dd * Ee * 2);
    bf16* u    = (bf16*)alloc((size_t)Mrows * Ee * 2);
    bf16* qb   = (bf16*)alloc((size_t)Mrows * Ss * 2);
    bf16* kb   = (bf16*)alloc((size_t)Mrows * Ss * 2);
    bf16* agg  = (bf16*)alloc((size_t)Mrows * Ee * 2);
    bf16* vT   = (bf16*)alloc((size_t)Bb * Ee * Kk * 2);

    int n1 = Ff * Dd;
    int n2 = Dd * Ee;
    int castBlocks = (n1 + n2 + 255) / 256;

    // fused rmsnorm (2 rows/block, float4) + weight casts
    pre_k<<<Mrows / 2 + castBlocks, 256, 0, stream>>>(x, g, xn, uv_w, uvwb, n1, o_w, owb, n2);

    // GEMM1: silu(xn @ uv_w^T) -> u, vT (transposed), q, k.  grid 17*128 = 2176
    gemm_nt<0><<<2176, 256, 0, stream>>>(
        xn, Dd, uvwb, Dd, Dd / BK, 17,
        u, vT, qb, kb, gamma, beta, nullptr, nullptr, nullptr);

    // fused attention: 256 blocks x 1024 threads
    attn_fused<<<256, 1024, 0, stream>>>(qb, kb, vT, u, agg);

    // GEMM4: out = x*res_scale + agg @ o_w^T.  grid 4*128 = 512
    gemm_nt<3><<<512, 256, 0, stream>>>(
        agg, Ee, owb, Ee, Ee / BK, 4,
        nullptr, nullptr, nullptr, nullptr, nullptr, nullptr,
        x, res_scale, out);
}